// Round 3
// baseline (151.215 us; speedup 1.0000x reference)
//
#include <hip/hip_runtime.h>

// Problem constants (fixed by setup_inputs): B=32, C=64, H=W=32, N=16 branches.
#define CH      64
#define BATCH   32
#define NBR     16
#define HW      1024          // H*W
#define NPC     32768         // elements per channel = BATCH*HW

// Native clang vector type: __builtin_nontemporal_store requires a pointer to
// int/float/vector-of-such; HIP's float4 (HIP_vector_type class) is rejected.
typedef float vfloat4 __attribute__((ext_vector_type(4)));

// ---------------------------------------------------------------------------
// Kernel A: per-(group, channel) partial sum / sumsq.
// grid = 512 blocks: c = blockIdx & 63, g = blockIdx >> 6 (8 batch groups of 4).
// Each block reads 4096 elements (1024 float4, fully coalesced) and writes one
// deterministic partial slot -> no atomics, no workspace zeroing required.
// ---------------------------------------------------------------------------
__global__ void __launch_bounds__(256) bn_partial(const float* __restrict__ x,
                                                  float* __restrict__ partials) {
    const int c = blockIdx.x & 63;
    const int g = blockIdx.x >> 6;        // 0..7
    const int t = threadIdx.x;            // 0..255

    float s = 0.f, sq = 0.f;
#pragma unroll
    for (int bb = 0; bb < 4; ++bb) {
        const int batch = g * 4 + bb;
        // channel chunk = HW floats = 256 float4; lane t takes float4 #t.
        const vfloat4 v = ((const vfloat4*)x)[(batch * CH + c) * 256 + t];
        s  += v.x + v.y + v.z + v.w;
        sq += v.x * v.x + v.y * v.y + v.z * v.z + v.w * v.w;
    }

    // wave(64)-level shuffle reduction
#pragma unroll
    for (int off = 32; off > 0; off >>= 1) {
        s  += __shfl_down(s, off);
        sq += __shfl_down(sq, off);
    }
    __shared__ float ls[4], lq[4];
    const int wave = t >> 6, lane = t & 63;
    if (lane == 0) { ls[wave] = s; lq[wave] = sq; }
    __syncthreads();
    if (t == 0) {
        partials[(g * CH + c) * 2 + 0] = ls[0] + ls[1] + ls[2] + ls[3];
        partials[(g * CH + c) * 2 + 1] = lq[0] + lq[1] + lq[2] + lq[3];
    }
}

// ---------------------------------------------------------------------------
// Kernel B: fused finalize + broadcast apply.
// grid = 2048 blocks, one block per (b, c) channel chunk (1024 floats).
// KEY: c and b derive from blockIdx.x ONLY -> all partials/gamma/beta loads
// and the mean/inv/scale/shift math are wave-uniform -> compiler emits s_load
// + scalar ALU (zero VMEM cost), instead of 32 broadcast vector loads/thread.
// Per-thread vector work: 1 float4 load of x, 16 FMA4, 16 float4 nt-stores
// (each store instr = 64 lanes x 16 B = 1 KB contiguous; per (block,n) the 4
// waves cover a 4 KB contiguous run).
// out flat index: ((b*N + n)*C + c)*HW + hw  ==  (b*1024 + n*64 + c)*1024 + hw
// ---------------------------------------------------------------------------
__global__ void __launch_bounds__(256) bn_apply(const float* __restrict__ x,
                                                const float* __restrict__ partials,
                                                const float* __restrict__ gamma,
                                                const float* __restrict__ beta,
                                                float* __restrict__ out) {
    const int c = blockIdx.x & 63;        // block-uniform
    const int b = blockIdx.x >> 6;        // block-uniform
    const int t = threadIdx.x;            // 0..255

    // Block-uniform statistics for channel c (scalar loads + scalar math).
    float S = 0.f, Q = 0.f;
#pragma unroll
    for (int g = 0; g < 8; ++g) {
        S += partials[(g * CH + c) * 2 + 0];
        Q += partials[(g * CH + c) * 2 + 1];
    }
    const float mean = S * (1.0f / NPC);
    const float inv  = rsqrtf(Q * (1.0f / NPC) - mean * mean + 1e-5f);

    const vfloat4 v = ((const vfloat4*)x)[(b * CH + c) * 256 + t];
    vfloat4* o4 = (vfloat4*)out;

#pragma unroll
    for (int n = 0; n < NBR; ++n) {
        const float a = gamma[n * CH + c] * inv;          // uniform -> scalar
        const float s = beta[n * CH + c] - a * mean;      // uniform -> scalar
        vfloat4 o;
        o.x = a * v.x + s;
        o.y = a * v.y + s;
        o.z = a * v.z + s;
        o.w = a * v.w + s;
        // out is 128 MB write-once: bypass L2 with non-temporal stores.
        __builtin_nontemporal_store(o, &o4[((b * 1024 + n * CH + c) << 8) + t]);
    }
}

extern "C" void kernel_launch(void* const* d_in, const int* in_sizes, int n_in,
                              void* d_out, int out_size, void* d_ws, size_t ws_size,
                              hipStream_t stream) {
    const float* x     = (const float*)d_in[0];   // [32,64,32,32]
    const float* gamma = (const float*)d_in[1];   // [16,64]
    const float* beta  = (const float*)d_in[2];   // [16,64]
    float* out = (float*)d_out;                   // [32,1024,32,32]
    float* partials = (float*)d_ws;               // 1024 floats (8g x 64c x {S,Q})

    bn_partial<<<512,  256, 0, stream>>>(x, partials);
    bn_apply  <<<2048, 256, 0, stream>>>(x, partials, gamma, beta, out);
}

// Round 4
// 147.732 us; speedup vs baseline: 1.0236x; 1.0236x over previous
//
#include <hip/hip_runtime.h>

// Problem constants (fixed by setup_inputs): B=32, C=64, H=W=32, N=16 branches.
#define CH      64
#define BATCH   32
#define NBR     16
#define HW      1024          // H*W
#define NPC     32768         // elements per channel = BATCH*HW

// Native clang vector type: __builtin_nontemporal_store requires a pointer to
// int/float/vector-of-such; HIP's float4 (HIP_vector_type class) is rejected.
typedef float vfloat4 __attribute__((ext_vector_type(4)));

// ---------------------------------------------------------------------------
// Kernel A: per-(group, channel) partial sum / sumsq.
// grid = 512 blocks: c = blockIdx & 63, g = blockIdx >> 6 (8 batch groups of 4).
// Each block reads 4096 elements (1024 float4, coalesced 1 KB/instr) and
// writes one deterministic partial slot -> no atomics, no ws zeroing needed.
// ---------------------------------------------------------------------------
__global__ void __launch_bounds__(256) bn_partial(const float* __restrict__ x,
                                                  float* __restrict__ partials) {
    const int c = blockIdx.x & 63;
    const int g = blockIdx.x >> 6;        // 0..7
    const int t = threadIdx.x;            // 0..255

    float s = 0.f, sq = 0.f;
#pragma unroll
    for (int bb = 0; bb < 4; ++bb) {
        const int batch = g * 4 + bb;
        const vfloat4 v = ((const vfloat4*)x)[(batch * CH + c) * 256 + t];
        s  += v.x + v.y + v.z + v.w;
        sq += v.x * v.x + v.y * v.y + v.z * v.z + v.w * v.w;
    }

#pragma unroll
    for (int off = 32; off > 0; off >>= 1) {
        s  += __shfl_down(s, off);
        sq += __shfl_down(sq, off);
    }
    __shared__ float ls[4], lq[4];
    const int wave = t >> 6, lane = t & 63;
    if (lane == 0) { ls[wave] = s; lq[wave] = sq; }
    __syncthreads();
    if (t == 0) {
        partials[(g * CH + c) * 2 + 0] = ls[0] + ls[1] + ls[2] + ls[3];
        partials[(g * CH + c) * 2 + 1] = lq[0] + lq[1] + lq[2] + lq[3];
    }
}

// ---------------------------------------------------------------------------
// Kernel B: OUTPUT-STATIONARY fused finalize + apply.
// Output = 32768 chunks of 4 KB (1024 floats), flat chunk oc = b*1024+n*64+c.
// grid = 8192 blocks x 256 threads; block j covers output chunks 4j..4j+3,
// one chunk per wave -> the store stream is PERFECTLY LINEAR across the grid
// (same pattern as the harness fill that measures 6.2 TB/s), vs R3's
// input-stationary 16-way 256KB-strided scatter.
// x chunk (b,c) is re-read by 16 blocks (n=0..15) at block-stride 16 ->
// same XCD (16 % 8 == 0) -> re-reads hit that XCD's L2; HBM read stays ~8MB.
// oc is wave-uniform; readfirstlane pins it to an SGPR so partials/gamma/beta
// become s_loads and the stats math is scalar (LLVM can't prove t>>6 uniform).
// ---------------------------------------------------------------------------
__global__ void __launch_bounds__(256) bn_apply(const float* __restrict__ x,
                                                const float* __restrict__ partials,
                                                const float* __restrict__ gamma,
                                                const float* __restrict__ beta,
                                                float* __restrict__ out) {
    const int t = threadIdx.x;
    const int l = t & 63;                                 // lane
    const int oc = __builtin_amdgcn_readfirstlane(blockIdx.x * 4 + (t >> 6));
    const int b = oc >> 10;
    const int n = (oc >> 6) & 15;
    const int c = oc & 63;

    // Block(-wave)-uniform statistics for channel c: scalar loads + scalar ALU.
    float S = 0.f, Q = 0.f;
#pragma unroll
    for (int g = 0; g < 8; ++g) {
        S += partials[(g * CH + c) * 2 + 0];
        Q += partials[(g * CH + c) * 2 + 1];
    }
    const float mean = S * (1.0f / NPC);
    const float inv  = rsqrtf(Q * (1.0f / NPC) - mean * mean + 1e-5f);
    const float a  = gamma[n * CH + c] * inv;
    const float sh = beta[n * CH + c] - a * mean;

    const vfloat4* x4 = (const vfloat4*)x;
    vfloat4*       o4 = (vfloat4*)out;
    const int xbase = (b * CH + c) * 256;   // x chunk for (b,c), in float4
    const int obase = oc * 256;             // out chunk, in float4

#pragma unroll
    for (int k = 0; k < 4; ++k) {
        const vfloat4 v = x4[xbase + l + 64 * k];   // coalesced, L2-resident
        vfloat4 o;
        o.x = a * v.x + sh;
        o.y = a * v.y + sh;
        o.z = a * v.z + sh;
        o.w = a * v.w + sh;
        // NT store: out is write-once; keep L2 free for the 16x-reused x.
        __builtin_nontemporal_store(o, &o4[obase + l + 64 * k]);
    }
}

extern "C" void kernel_launch(void* const* d_in, const int* in_sizes, int n_in,
                              void* d_out, int out_size, void* d_ws, size_t ws_size,
                              hipStream_t stream) {
    const float* x     = (const float*)d_in[0];   // [32,64,32,32]
    const float* gamma = (const float*)d_in[1];   // [16,64]
    const float* beta  = (const float*)d_in[2];   // [16,64]
    float* out = (float*)d_out;                   // [32,1024,32,32]
    float* partials = (float*)d_ws;               // 1024 floats (8g x 64c x {S,Q})

    bn_partial<<<512,  256, 0, stream>>>(x, partials);
    bn_apply  <<<8192, 256, 0, stream>>>(x, partials, gamma, beta, out);
}